// Round 1
// baseline (299.092 us; speedup 1.0000x reference)
//
#include <hip/hip_runtime.h>
#include <hip/hip_bf16.h>
#include <math.h>

// Problem constants
#define NB     4        // batches
#define NTOK   4096     // sequence length
#define IND    1024     // in_dim
#define LAT    128      // latent dim
#define MTOT   (NB*NTOK)  // 16384 total rows

typedef short bf16x8 __attribute__((ext_vector_type(8)));
typedef float f32x4  __attribute__((ext_vector_type(4)));

__device__ __forceinline__ unsigned short f2bf(float x) {
    union { float f; unsigned int u; } v; v.f = x;
    unsigned int r = v.u + 0x7FFFu + ((v.u >> 16) & 1u);  // RNE
    return (unsigned short)(r >> 16);
}

// ---------------------------------------------------------------------------
// proj_kernel: OUT = X[M x 1024] @ W^T[1024 x 128] + bias, output bf16.
// TRANS=false: row-major [M][128] (Kp). TRANS=true: per-batch transposed
// [b][128][4096] (VpT) so attention PV B-operand reads are contiguous.
// BM=64, BN=128 (full), BK=32; 256 threads = 4 waves (2x2), wave tile 32x64.
// ---------------------------------------------------------------------------
template<bool TRANS>
__global__ __launch_bounds__(256) void proj_kernel(const float* __restrict__ X,
                                                   const float* __restrict__ W,
                                                   const float* __restrict__ bias,
                                                   unsigned short* __restrict__ out) {
    __shared__ short Al[64][40];    // 32 k + 8 pad -> 2-way-free bank pattern
    __shared__ short Bl[128][40];
    const int t  = threadIdx.x;
    const int l  = t & 63;
    const int w  = t >> 6;
    const int br = blockIdx.x;           // 256 blocks x 64 rows
    const int wr = (w >> 1) * 32;
    const int wc = (w & 1) * 64;
    const int lrow = l & 15, lhi = l >> 4;

    f32x4 acc[2][4] = {};

    for (int k0 = 0; k0 < IND; k0 += 32) {
        // stage A: 64x32 f32 -> bf16 (512 float4 chunks / 256 threads)
        #pragma unroll
        for (int j = 0; j < 2; ++j) {
            int c = t + j * 256;
            int row = c >> 3, ch = c & 7;
            float4 v = *reinterpret_cast<const float4*>(
                &X[(size_t)(br * 64 + row) * IND + k0 + ch * 4]);
            union { unsigned short s[4]; unsigned long long q; } pk;
            pk.s[0] = f2bf(v.x); pk.s[1] = f2bf(v.y);
            pk.s[2] = f2bf(v.z); pk.s[3] = f2bf(v.w);
            *reinterpret_cast<unsigned long long*>(&Al[row][ch * 4]) = pk.q;
        }
        // stage B: 128x32 f32 -> bf16 (1024 chunks)
        #pragma unroll
        for (int j = 0; j < 4; ++j) {
            int c = t + j * 256;
            int row = c >> 3, ch = c & 7;
            float4 v = *reinterpret_cast<const float4*>(
                &W[(size_t)row * IND + k0 + ch * 4]);
            union { unsigned short s[4]; unsigned long long q; } pk;
            pk.s[0] = f2bf(v.x); pk.s[1] = f2bf(v.y);
            pk.s[2] = f2bf(v.z); pk.s[3] = f2bf(v.w);
            *reinterpret_cast<unsigned long long*>(&Bl[row][ch * 4]) = pk.q;
        }
        __syncthreads();

        bf16x8 a[2], b[4];
        #pragma unroll
        for (int m = 0; m < 2; ++m)
            a[m] = *reinterpret_cast<const bf16x8*>(&Al[wr + m * 16 + lrow][lhi * 8]);
        #pragma unroll
        for (int n = 0; n < 4; ++n)
            b[n] = *reinterpret_cast<const bf16x8*>(&Bl[wc + n * 16 + lrow][lhi * 8]);
        #pragma unroll
        for (int m = 0; m < 2; ++m)
            #pragma unroll
            for (int n = 0; n < 4; ++n)
                acc[m][n] = __builtin_amdgcn_mfma_f32_16x16x32_bf16(a[m], b[n], acc[m][n], 0, 0, 0);
        __syncthreads();
    }

    // epilogue: bias + bf16 store
    #pragma unroll
    for (int m = 0; m < 2; ++m) {
        int row0 = br * 64 + wr + m * 16 + (lhi << 2);
        #pragma unroll
        for (int n = 0; n < 4; ++n) {
            int col = wc + n * 16 + lrow;
            float bv = bias[col];
            if (!TRANS) {
                #pragma unroll
                for (int r = 0; r < 4; ++r)
                    out[(size_t)(row0 + r) * LAT + col] = f2bf(acc[m][n][r] + bv);
            } else {
                int batch = row0 >> 12;
                int nb    = row0 & 4095;   // rows 0..3 stay in-batch (4-aligned)
                union { unsigned short s[4]; unsigned long long q; } pk;
                #pragma unroll
                for (int r = 0; r < 4; ++r) pk.s[r] = f2bf(acc[m][n][r] + bv);
                *reinterpret_cast<unsigned long long*>(
                    &out[(size_t)batch * (LAT * NTOK) + (size_t)col * NTOK + nb]) = pk.q;
            }
        }
    }
}

// ---------------------------------------------------------------------------
// qp_kernel: Qp = Kp(bf16)[M x 128] @ Wq^T + bq, bf16 row-major out.
// Same tile structure, K=128 (4 iters of 32).
// ---------------------------------------------------------------------------
__global__ __launch_bounds__(256) void qp_kernel(const unsigned short* __restrict__ Kp,
                                                 const float* __restrict__ Wq,
                                                 const float* __restrict__ bq,
                                                 unsigned short* __restrict__ out) {
    __shared__ short Al[64][40];
    __shared__ short Bl[128][40];
    const int t  = threadIdx.x;
    const int l  = t & 63;
    const int w  = t >> 6;
    const int br = blockIdx.x;
    const int wr = (w >> 1) * 32;
    const int wc = (w & 1) * 64;
    const int lrow = l & 15, lhi = l >> 4;

    f32x4 acc[2][4] = {};

    for (int k0 = 0; k0 < LAT; k0 += 32) {
        // stage A: 64x32 bf16 (256 chunks of 8 = exactly 256 threads)
        {
            int row = t >> 2, ch = t & 3;
            *reinterpret_cast<bf16x8*>(&Al[row][ch * 8]) =
                *reinterpret_cast<const bf16x8*>(
                    &Kp[(size_t)(br * 64 + row) * LAT + k0 + ch * 8]);
        }
        // stage B: Wq 128x32 f32 -> bf16
        #pragma unroll
        for (int j = 0; j < 4; ++j) {
            int c = t + j * 256;
            int row = c >> 3, ch = c & 7;
            float4 v = *reinterpret_cast<const float4*>(
                &Wq[(size_t)row * LAT + k0 + ch * 4]);
            union { unsigned short s[4]; unsigned long long q; } pk;
            pk.s[0] = f2bf(v.x); pk.s[1] = f2bf(v.y);
            pk.s[2] = f2bf(v.z); pk.s[3] = f2bf(v.w);
            *reinterpret_cast<unsigned long long*>(&Bl[row][ch * 4]) = pk.q;
        }
        __syncthreads();

        bf16x8 a[2], b[4];
        #pragma unroll
        for (int m = 0; m < 2; ++m)
            a[m] = *reinterpret_cast<const bf16x8*>(&Al[wr + m * 16 + lrow][lhi * 8]);
        #pragma unroll
        for (int n = 0; n < 4; ++n)
            b[n] = *reinterpret_cast<const bf16x8*>(&Bl[wc + n * 16 + lrow][lhi * 8]);
        #pragma unroll
        for (int m = 0; m < 2; ++m)
            #pragma unroll
            for (int n = 0; n < 4; ++n)
                acc[m][n] = __builtin_amdgcn_mfma_f32_16x16x32_bf16(a[m], b[n], acc[m][n], 0, 0, 0);
        __syncthreads();
    }

    #pragma unroll
    for (int m = 0; m < 2; ++m) {
        int row0 = br * 64 + wr + m * 16 + (lhi << 2);
        #pragma unroll
        for (int n = 0; n < 4; ++n) {
            int col = wc + n * 16 + lrow;
            float bv = bq[col];
            #pragma unroll
            for (int r = 0; r < 4; ++r)
                out[(size_t)(row0 + r) * LAT + col] = f2bf(acc[m][n][r] + bv);
        }
    }
}

// ---------------------------------------------------------------------------
// attn_kernel: Y = softmax(Qp·Kp^T / 64, axis=-1) @ Vp  (per batch).
// 256 blocks = 4 batches x 64 Q-tiles of 64 rows; 4 waves x 16 Q-rows each.
// KV tiles of 64. Online softmax (running m,l per row, 16-lane shuffles).
// ---------------------------------------------------------------------------
__global__ __launch_bounds__(256) void attn_kernel(const unsigned short* __restrict__ Qp,
                                                   const unsigned short* __restrict__ Kp,
                                                   const unsigned short* __restrict__ VpT,
                                                   float* __restrict__ Y) {
    __shared__ short Kl[64][136];   // [k][d], +8 pad
    __shared__ short Vl[128][72];   // [d][k], +8 pad
    __shared__ short Pl[4][16][72]; // per-wave P tile [q][k], +8 pad
    const int t = threadIdx.x, l = t & 63, w = t >> 6;
    const int bb = blockIdx.x >> 6;
    const int qt = blockIdx.x & 63;
    const size_t base = (size_t)bb * (NTOK * LAT);
    const int lrow = l & 15, lhi = l >> 4;

    // Q fragments in registers: rows qt*64 + w*16 + lrow, 4 d-chunks of 32
    bf16x8 qf[4];
    #pragma unroll
    for (int c = 0; c < 4; ++c)
        qf[c] = *reinterpret_cast<const bf16x8*>(
            &Qp[base + (size_t)(qt * 64 + w * 16 + lrow) * LAT + c * 32 + lhi * 8]);

    f32x4 oacc[8] = {};
    float mrun[4], lrun[4];
    #pragma unroll
    for (int r = 0; r < 4; ++r) { mrun[r] = -INFINITY; lrun[r] = 0.f; }

    const float SC  = 1.0f / 64.0f;          // 1/sqrt(4096)
    const float L2E = 1.4426950408889634f;

    for (int kt = 0; kt < 64; ++kt) {
        // stage K tile [64][128] bf16
        #pragma unroll
        for (int j = 0; j < 4; ++j) {
            int c = t + j * 256;
            int row = c >> 4, ch = c & 15;
            *reinterpret_cast<bf16x8*>(&Kl[row][ch * 8]) =
                *reinterpret_cast<const bf16x8*>(
                    &Kp[base + (size_t)(kt * 64 + row) * LAT + ch * 8]);
        }
        // stage VpT tile [128][64] bf16
        #pragma unroll
        for (int j = 0; j < 4; ++j) {
            int c = t + j * 256;
            int row = c >> 3, ch = c & 7;
            *reinterpret_cast<bf16x8*>(&Vl[row][ch * 8]) =
                *reinterpret_cast<const bf16x8*>(
                    &VpT[base + (size_t)row * NTOK + kt * 64 + ch * 8]);
        }
        __syncthreads();

        // S = Q·K^T  (16 q-rows x 64 k-cols per wave)
        f32x4 sacc[4];
        #pragma unroll
        for (int ks = 0; ks < 4; ++ks) {
            f32x4 s = {};
            #pragma unroll
            for (int c = 0; c < 4; ++c) {
                bf16x8 kf = *reinterpret_cast<const bf16x8*>(
                    &Kl[ks * 16 + lrow][c * 32 + lhi * 8]);
                s = __builtin_amdgcn_mfma_f32_16x16x32_bf16(qf[c], kf, s, 0, 0, 0);
            }
            #pragma unroll
            for (int r = 0; r < 4; ++r) s[r] *= SC;
            sacc[ks] = s;
        }

        // online softmax: rows = lhi*4 + r, cols spread over 16 lanes x 4 ks
        float al[4];
        #pragma unroll
        for (int r = 0; r < 4; ++r) {
            float mx = fmaxf(fmaxf(sacc[0][r], sacc[1][r]),
                             fmaxf(sacc[2][r], sacc[3][r]));
            #pragma unroll
            for (int off = 1; off < 16; off <<= 1)
                mx = fmaxf(mx, __shfl_xor(mx, off));
            float mnew = fmaxf(mrun[r], mx);
            al[r] = exp2f((mrun[r] - mnew) * L2E);
            mrun[r] = mnew;
        }
        float ps[4] = {0.f, 0.f, 0.f, 0.f};
        #pragma unroll
        for (int ks = 0; ks < 4; ++ks)
            #pragma unroll
            for (int r = 0; r < 4; ++r) {
                float p = exp2f((sacc[ks][r] - mrun[r]) * L2E);
                ps[r] += p;
                Pl[w][lhi * 4 + r][ks * 16 + lrow] = (short)f2bf(p);
            }
        #pragma unroll
        for (int r = 0; r < 4; ++r) {
            float s = ps[r];
            #pragma unroll
            for (int off = 1; off < 16; off <<= 1)
                s += __shfl_xor(s, off);
            lrun[r] = lrun[r] * al[r] + s;
        }
        #pragma unroll
        for (int ds = 0; ds < 8; ++ds)
            #pragma unroll
            for (int r = 0; r < 4; ++r) oacc[ds][r] *= al[r];

        // Pl writes -> Pl reads are cross-lane within the wave: stop the
        // compiler from reordering (DS pipe is in-order per wave in HW).
        asm volatile("s_waitcnt lgkmcnt(0)" ::: "memory");
        __builtin_amdgcn_sched_barrier(0);

        // O += P @ V
        #pragma unroll
        for (int ds = 0; ds < 8; ++ds) {
            #pragma unroll
            for (int kc = 0; kc < 2; ++kc) {
                bf16x8 pf = *reinterpret_cast<const bf16x8*>(
                    &Pl[w][lrow][kc * 32 + lhi * 8]);
                bf16x8 vf = *reinterpret_cast<const bf16x8*>(
                    &Vl[ds * 16 + lrow][kc * 32 + lhi * 8]);
                oacc[ds] = __builtin_amdgcn_mfma_f32_16x16x32_bf16(pf, vf, oacc[ds], 0, 0, 0);
            }
        }
        __syncthreads();
    }

    // epilogue: divide by l, f32 store
    #pragma unroll
    for (int r = 0; r < 4; ++r) {
        float inv = 1.0f / lrun[r];
        int row = qt * 64 + w * 16 + lhi * 4 + r;
        #pragma unroll
        for (int ds = 0; ds < 8; ++ds)
            Y[base + (size_t)row * LAT + ds * 16 + lrow] = oacc[ds][r] * inv;
    }
}

// ---------------------------------------------------------------------------
extern "C" void kernel_launch(void* const* d_in, const int* in_sizes, int n_in,
                              void* d_out, int out_size, void* d_ws, size_t ws_size,
                              hipStream_t stream) {
    const float* Q  = (const float*)d_in[0];
    // d_in[1] = K input is IGNORED by the reference (quirk: Kp projected from Q)
    const float* V  = (const float*)d_in[2];
    const float* Wk = (const float*)d_in[3];
    const float* bk = (const float*)d_in[4];
    const float* Wq = (const float*)d_in[5];
    const float* bq = (const float*)d_in[6];
    const float* Wv = (const float*)d_in[7];
    const float* bv = (const float*)d_in[8];

    // workspace: Kp (4MB) | Qp (4MB) | VpT (4MB), all bf16
    unsigned short* Kp  = (unsigned short*)d_ws;
    unsigned short* Qp  = Kp + (size_t)MTOT * LAT;
    unsigned short* VpT = Qp + (size_t)MTOT * LAT;
    float* Yo = (float*)d_out;

    proj_kernel<false><<<dim3(256), dim3(256), 0, stream>>>(Q, Wk, bk, Kp);
    proj_kernel<true ><<<dim3(256), dim3(256), 0, stream>>>(V, Wv, bv, VpT);
    qp_kernel<<<dim3(256), dim3(256), 0, stream>>>(Kp, Wq, bq, Qp);
    attn_kernel<<<dim3(256), dim3(256), 0, stream>>>(Qp, Kp, VpT, Yo);
}

// Round 2
// 294.590 us; speedup vs baseline: 1.0153x; 1.0153x over previous
//
#include <hip/hip_runtime.h>
#include <hip/hip_bf16.h>
#include <math.h>

// Problem constants
#define NB     4
#define NTOK   4096
#define IND    1024
#define LAT    128
#define MTOT   (NB*NTOK)
#define SPLIT  4
#define L2E    1.4426950408889634f

typedef short bf16x8 __attribute__((ext_vector_type(8)));
typedef float f32x4  __attribute__((ext_vector_type(4)));

__device__ __forceinline__ unsigned short f2bf(float x) {
    union { float f; unsigned int u; } v; v.f = x;
    unsigned int r = v.u + 0x7FFFu + ((v.u >> 16) & 1u);  // RNE
    return (unsigned short)(r >> 16);
}

// ===========================================================================
// fuse_w: Wcomb rows 0..127 = bf16(Wk); rows 128..255 = bf16(Wq @ Wk);
// bqk = Wq @ bk + bq.  grid (4,128) x 256.
// ===========================================================================
__global__ __launch_bounds__(256) void fuse_w(const float* __restrict__ Wq,
                                              const float* __restrict__ Wk,
                                              const float* __restrict__ bk,
                                              const float* __restrict__ bq,
                                              unsigned short* __restrict__ Wcomb,
                                              float* __restrict__ bqk) {
    const int o = blockIdx.y;                       // 0..127
    const int i = blockIdx.x * 256 + threadIdx.x;   // 0..1023
    Wcomb[(size_t)o * IND + i] = f2bf(Wk[(size_t)o * IND + i]);
    float acc = 0.f;
    #pragma unroll 8
    for (int l = 0; l < 128; ++l)
        acc = fmaf(Wq[o * 128 + l], Wk[(size_t)l * IND + i], acc);
    Wcomb[(size_t)(128 + o) * IND + i] = f2bf(acc);
    if (blockIdx.x == 0 && threadIdx.x == 0) {
        float b = bq[o];
        for (int l = 0; l < 128; ++l) b = fmaf(Wq[o * 128 + l], bk[l], b);
        bqk[o] = b;
    }
}

// ===========================================================================
// proj_qk: [Kp | Qp] = Q @ [Wk | Wqk]^T + [bk | bqk].  BM=32, BN=256, BK=64.
// 512 blocks x 256 thr (4 waves: 2 row-groups x 2 col-panels). XOR-swizzled LDS.
// ===========================================================================
__global__ __launch_bounds__(256) void proj_qk(const float* __restrict__ X,
                                               const unsigned short* __restrict__ Wcomb,
                                               const float* __restrict__ bk,
                                               const float* __restrict__ bqk,
                                               unsigned short* __restrict__ Kp,
                                               unsigned short* __restrict__ Qp) {
    __shared__ char lds[4096 + 32768];   // A [32][64]bf16, B [256][64]bf16
    const int t = threadIdx.x, l = t & 63, w = t >> 6;
    const int br = blockIdx.x;
    const int lrow = l & 15, lhi = l >> 4;
    const int wr = (w >> 1) * 16, wc = (w & 1) * 128;

    f32x4 acc[8] = {};

    for (int k0 = 0; k0 < IND; k0 += 64) {
        #pragma unroll
        for (int j = 0; j < 2; ++j) {   // A: 32x64 f32 -> bf16
            int c = t + j * 256, row = c >> 4, ch = c & 15;
            float4 v = *(const float4*)&X[(size_t)(br * 32 + row) * IND + k0 + ch * 4];
            union { unsigned short s[4]; unsigned long long q; } pk;
            pk.s[0] = f2bf(v.x); pk.s[1] = f2bf(v.y);
            pk.s[2] = f2bf(v.z); pk.s[3] = f2bf(v.w);
            *(unsigned long long*)(lds + ((row * 128 + ch * 8) ^ ((row & 7) << 4))) = pk.q;
        }
        #pragma unroll
        for (int j = 0; j < 8; ++j) {   // B: 256x64 bf16
            int c = t + j * 256, row = c >> 3, ch = c & 7;
            *(bf16x8*)(lds + 4096 + ((row * 128 + ch * 16) ^ ((row & 7) << 4))) =
                *(const bf16x8*)&Wcomb[(size_t)row * IND + k0 + ch * 8];
        }
        __syncthreads();

        const int arow = wr + lrow;
        bf16x8 a[2];
        #pragma unroll
        for (int kk = 0; kk < 2; ++kk)
            a[kk] = *(const bf16x8*)(lds + ((arow * 128 + kk * 64 + lhi * 16) ^ ((arow & 7) << 4)));
        #pragma unroll
        for (int n = 0; n < 8; ++n) {
            const int brow = wc + n * 16 + lrow;
            #pragma unroll
            for (int kk = 0; kk < 2; ++kk) {
                bf16x8 b = *(const bf16x8*)(lds + 4096 +
                    ((brow * 128 + kk * 64 + lhi * 16) ^ ((brow & 7) << 4)));
                acc[n] = __builtin_amdgcn_mfma_f32_16x16x32_bf16(a[kk], b, acc[n], 0, 0, 0);
            }
        }
        __syncthreads();
    }

    const int row0 = br * 32 + wr + lhi * 4;
    unsigned short* out = (wc == 0) ? Kp : Qp;
    const float* bias = (wc == 0) ? bk : bqk;
    #pragma unroll
    for (int n = 0; n < 8; ++n) {
        int col = n * 16 + lrow;
        float bv = bias[col];
        #pragma unroll
        for (int r = 0; r < 4; ++r)
            out[(size_t)(row0 + r) * LAT + col] = f2bf(acc[n][r] + bv);
    }
}

// ===========================================================================
// proj_v: VpT[b][d][n] = (V @ Wv^T + bv)^T.  BM=32, BN=128, BK=64. 512 blocks.
// ===========================================================================
__global__ __launch_bounds__(256) void proj_v(const float* __restrict__ X,
                                              const float* __restrict__ Wv,
                                              const float* __restrict__ bv,
                                              unsigned short* __restrict__ VpT) {
    __shared__ char lds[4096 + 16384];   // A [32][64], B [128][64]
    const int t = threadIdx.x, l = t & 63, w = t >> 6;
    const int br = blockIdx.x;
    const int lrow = l & 15, lhi = l >> 4;
    const int wr = (w >> 1) * 16, wc = (w & 1) * 64;

    f32x4 acc[4] = {};

    for (int k0 = 0; k0 < IND; k0 += 64) {
        #pragma unroll
        for (int j = 0; j < 2; ++j) {   // A: 32x64 f32 -> bf16
            int c = t + j * 256, row = c >> 4, ch = c & 15;
            float4 v = *(const float4*)&X[(size_t)(br * 32 + row) * IND + k0 + ch * 4];
            union { unsigned short s[4]; unsigned long long q; } pk;
            pk.s[0] = f2bf(v.x); pk.s[1] = f2bf(v.y);
            pk.s[2] = f2bf(v.z); pk.s[3] = f2bf(v.w);
            *(unsigned long long*)(lds + ((row * 128 + ch * 8) ^ ((row & 7) << 4))) = pk.q;
        }
        #pragma unroll
        for (int j = 0; j < 8; ++j) {   // B: 128x64 f32 -> bf16
            int c = t + j * 256, row = c >> 4, ch = c & 15;
            float4 v = *(const float4*)&Wv[(size_t)row * IND + k0 + ch * 4];
            union { unsigned short s[4]; unsigned long long q; } pk;
            pk.s[0] = f2bf(v.x); pk.s[1] = f2bf(v.y);
            pk.s[2] = f2bf(v.z); pk.s[3] = f2bf(v.w);
            *(unsigned long long*)(lds + 4096 + ((row * 128 + ch * 8) ^ ((row & 7) << 4))) = pk.q;
        }
        __syncthreads();

        const int arow = wr + lrow;
        bf16x8 a[2];
        #pragma unroll
        for (int kk = 0; kk < 2; ++kk)
            a[kk] = *(const bf16x8*)(lds + ((arow * 128 + kk * 64 + lhi * 16) ^ ((arow & 7) << 4)));
        #pragma unroll
        for (int n = 0; n < 4; ++n) {
            const int brow = wc + n * 16 + lrow;
            #pragma unroll
            for (int kk = 0; kk < 2; ++kk) {
                bf16x8 b = *(const bf16x8*)(lds + 4096 +
                    ((brow * 128 + kk * 64 + lhi * 16) ^ ((brow & 7) << 4)));
                acc[n] = __builtin_amdgcn_mfma_f32_16x16x32_bf16(a[kk], b, acc[n], 0, 0, 0);
            }
        }
        __syncthreads();
    }

    const int row0 = br * 32 + wr + lhi * 4;   // token index (4-aligned)
    const int batch = row0 >> 12, tok = row0 & 4095;
    #pragma unroll
    for (int n = 0; n < 4; ++n) {
        int col = wc + n * 16 + lrow;
        float bv_ = bv[col];
        union { unsigned short s[4]; unsigned long long q; } pk;
        #pragma unroll
        for (int r = 0; r < 4; ++r) pk.s[r] = f2bf(acc[n][r] + bv_);
        *(unsigned long long*)&VpT[(size_t)batch * (LAT * NTOK) + (size_t)col * NTOK + tok] = pk.q;
    }
}

// ===========================================================================
// attn_part<NSPLIT>: flash attention over a KV chunk of NTOK/NSPLIT keys.
// grid (64 qtiles, NB, NSPLIT) x 256 thr. 40KB swizzled LDS -> 4 blocks/CU.
// NSPLIT==1 writes normalized Y; else unnormalized partials + (m,l).
// ===========================================================================
template<int NSPLIT>
__global__ __launch_bounds__(256, 4) void attn_part(const unsigned short* __restrict__ Qp,
                                                    const unsigned short* __restrict__ Kp,
                                                    const unsigned short* __restrict__ VpT,
                                                    float* __restrict__ Out,
                                                    float2* __restrict__ ml) {
    __shared__ char lds[40960];   // K [64][128] @0, V [128][64] @16384, P 4x[16][64] @32768
    const int t = threadIdx.x, l = t & 63, w = t >> 6;
    const int qt = blockIdx.x, bb = blockIdx.y, ck = blockIdx.z;
    const size_t base = (size_t)bb * ((size_t)NTOK * LAT);
    const size_t vbase = (size_t)bb * ((size_t)LAT * NTOK);
    const int lrow = l & 15, lhi = l >> 4;
    const int k_base = ck * (NTOK / NSPLIT);
    const float SC = 1.0f / 64.0f;   // 1/sqrt(4096)

    bf16x8 qf[4];
    #pragma unroll
    for (int c = 0; c < 4; ++c)
        qf[c] = *(const bf16x8*)&Qp[base + (size_t)(qt * 64 + w * 16 + lrow) * LAT + c * 32 + lhi * 8];

    f32x4 oacc[8] = {};
    float mrun[4], lrun[4];
    #pragma unroll
    for (int r = 0; r < 4; ++r) { mrun[r] = -INFINITY; lrun[r] = 0.f; }

    for (int kt = 0; kt < (NTOK / NSPLIT) / 64; ++kt) {
        const int k_lo = k_base + kt * 64;
        #pragma unroll
        for (int j = 0; j < 4; ++j) {   // K tile [64][128]
            int c = t + j * 256, row = c >> 4, ch = c & 15;
            *(bf16x8*)(lds + ((row * 256 + ch * 16) ^ ((row & 7) << 4))) =
                *(const bf16x8*)&Kp[base + (size_t)(k_lo + row) * LAT + ch * 8];
        }
        #pragma unroll
        for (int j = 0; j < 4; ++j) {   // V tile [128][64]
            int c = t + j * 256, row = c >> 3, ch = c & 7;
            *(bf16x8*)(lds + 16384 + ((row * 128 + ch * 16) ^ ((row & 7) << 4))) =
                *(const bf16x8*)&VpT[vbase + (size_t)row * NTOK + k_lo + ch * 8];
        }
        __syncthreads();

        // S = Q K^T
        f32x4 sacc[4];
        #pragma unroll
        for (int ks = 0; ks < 4; ++ks) {
            f32x4 s = {};
            #pragma unroll
            for (int c = 0; c < 4; ++c) {
                bf16x8 kf = *(const bf16x8*)(lds +
                    (((ks * 16 + lrow) * 256 + c * 64 + lhi * 16) ^ ((lrow & 7) << 4)));
                s = __builtin_amdgcn_mfma_f32_16x16x32_bf16(qf[c], kf, s, 0, 0, 0);
            }
            #pragma unroll
            for (int r = 0; r < 4; ++r) s[r] *= SC;
            sacc[ks] = s;
        }

        // online softmax (rows = lhi*4+r; cols over 16 lanes x 4 ks)
        float al[4];
        #pragma unroll
        for (int r = 0; r < 4; ++r) {
            float mx = fmaxf(fmaxf(sacc[0][r], sacc[1][r]),
                             fmaxf(sacc[2][r], sacc[3][r]));
            #pragma unroll
            for (int off = 1; off < 16; off <<= 1)
                mx = fmaxf(mx, __shfl_xor(mx, off));
            float mnew = fmaxf(mrun[r], mx);
            al[r] = exp2f((mrun[r] - mnew) * L2E);
            mrun[r] = mnew;
        }
        float ps[4] = {0.f, 0.f, 0.f, 0.f};
        const int plb = 32768 + w * 2048;
        #pragma unroll
        for (int ks = 0; ks < 4; ++ks)
            #pragma unroll
            for (int r = 0; r < 4; ++r) {
                float p = exp2f((sacc[ks][r] - mrun[r]) * L2E);
                ps[r] += p;
                int q = lhi * 4 + r;
                *(unsigned short*)(lds + plb +
                    ((q * 128 + (ks * 16 + lrow) * 2) ^ ((q & 7) << 4))) = f2bf(p);
            }
        #pragma unroll
        for (int r = 0; r < 4; ++r) {
            float s = ps[r];
            #pragma unroll
            for (int off = 1; off < 16; off <<= 1)
                s += __shfl_xor(s, off);
            lrun[r] = lrun[r] * al[r] + s;
        }
        #pragma unroll
        for (int ds = 0; ds < 8; ++ds)
            #pragma unroll
            for (int r = 0; r < 4; ++r) oacc[ds][r] *= al[r];

        // wave-internal LDS write->read ordering for P
        asm volatile("s_waitcnt lgkmcnt(0)" ::: "memory");
        __builtin_amdgcn_sched_barrier(0);

        bf16x8 pf0 = *(const bf16x8*)(lds + plb + ((lrow * 128 + lhi * 16) ^ ((lrow & 7) << 4)));
        bf16x8 pf1 = *(const bf16x8*)(lds + plb + ((lrow * 128 + 64 + lhi * 16) ^ ((lrow & 7) << 4)));
        #pragma unroll
        for (int ds = 0; ds < 8; ++ds) {
            const int vr = ds * 16 + lrow;
            bf16x8 vf0 = *(const bf16x8*)(lds + 16384 + ((vr * 128 + lhi * 16) ^ ((lrow & 7) << 4)));
            bf16x8 vf1 = *(const bf16x8*)(lds + 16384 + ((vr * 128 + 64 + lhi * 16) ^ ((lrow & 7) << 4)));
            oacc[ds] = __builtin_amdgcn_mfma_f32_16x16x32_bf16(pf0, vf0, oacc[ds], 0, 0, 0);
            oacc[ds] = __builtin_amdgcn_mfma_f32_16x16x32_bf16(pf1, vf1, oacc[ds], 0, 0, 0);
        }
        __syncthreads();
    }

    if constexpr (NSPLIT == 1) {
        #pragma unroll
        for (int r = 0; r < 4; ++r) {
            float inv = 1.0f / lrun[r];
            int row = qt * 64 + w * 16 + lhi * 4 + r;
            #pragma unroll
            for (int ds = 0; ds < 8; ++ds)
                Out[base + (size_t)row * LAT + ds * 16 + lrow] = oacc[ds][r] * inv;
        }
    } else {
        const size_t pbase = (size_t)ck * MTOT + (size_t)bb * NTOK;
        #pragma unroll
        for (int r = 0; r < 4; ++r) {
            int row = qt * 64 + w * 16 + lhi * 4 + r;
            #pragma unroll
            for (int ds = 0; ds < 8; ++ds)
                Out[(pbase + row) * LAT + ds * 16 + lrow] = oacc[ds][r];
            if (lrow == 0) ml[pbase + row] = make_float2(mrun[r], lrun[r]);
        }
    }
}

// ===========================================================================
// merge_k: Y = (sum_c e^{m_c-M} O_c) / (sum_c e^{m_c-M} l_c). 2048 blocks.
// ===========================================================================
__global__ __launch_bounds__(256) void merge_k(const float* __restrict__ Opart,
                                               const float2* __restrict__ ml,
                                               float* __restrict__ Y) {
    const int t = threadIdx.x;
    const int row = blockIdx.x * 8 + (t >> 5);
    const int c4 = (t & 31) * 4;
    float m[SPLIT], li[SPLIT], wg[SPLIT];
    float M = -INFINITY;
    #pragma unroll
    for (int c = 0; c < SPLIT; ++c) {
        float2 p = ml[(size_t)c * MTOT + row];
        m[c] = p.x; li[c] = p.y; M = fmaxf(M, m[c]);
    }
    float L = 0.f;
    #pragma unroll
    for (int c = 0; c < SPLIT; ++c) { wg[c] = exp2f((m[c] - M) * L2E); L += wg[c] * li[c]; }
    f32x4 acc = {};
    #pragma unroll
    for (int c = 0; c < SPLIT; ++c) {
        f32x4 v = *(const f32x4*)&Opart[((size_t)c * MTOT + row) * LAT + c4];
        acc += v * wg[c];
    }
    const float inv = 1.f / L;
    *(f32x4*)&Y[(size_t)row * LAT + c4] = acc * inv;
}

// ===========================================================================
// Fallback (round-1 proven kernels) for small ws_size
// ===========================================================================
template<bool TRANS>
__global__ __launch_bounds__(256) void proj_kernel(const float* __restrict__ X,
                                                   const float* __restrict__ W,
                                                   const float* __restrict__ bias,
                                                   unsigned short* __restrict__ out) {
    __shared__ short Al[64][40];
    __shared__ short Bl[128][40];
    const int t = threadIdx.x, l = t & 63, w = t >> 6;
    const int br = blockIdx.x;
    const int wr = (w >> 1) * 32, wc = (w & 1) * 64;
    const int lrow = l & 15, lhi = l >> 4;
    f32x4 acc[2][4] = {};
    for (int k0 = 0; k0 < IND; k0 += 32) {
        #pragma unroll
        for (int j = 0; j < 2; ++j) {
            int c = t + j * 256, row = c >> 3, ch = c & 7;
            float4 v = *(const float4*)&X[(size_t)(br * 64 + row) * IND + k0 + ch * 4];
            union { unsigned short s[4]; unsigned long long q; } pk;
            pk.s[0] = f2bf(v.x); pk.s[1] = f2bf(v.y); pk.s[2] = f2bf(v.z); pk.s[3] = f2bf(v.w);
            *(unsigned long long*)&Al[row][ch * 4] = pk.q;
        }
        #pragma unroll
        for (int j = 0; j < 4; ++j) {
            int c = t + j * 256, row = c >> 3, ch = c & 7;
            float4 v = *(const float4*)&W[(size_t)row * IND + k0 + ch * 4];
            union { unsigned short s[4]; unsigned long long q; } pk;
            pk.s[0] = f2bf(v.x); pk.s[1] = f2bf(v.y); pk.s[2] = f2bf(v.z); pk.s[3] = f2bf(v.w);
            *(unsigned long long*)&Bl[row][ch * 4] = pk.q;
        }
        __syncthreads();
        bf16x8 a[2], b[4];
        #pragma unroll
        for (int m = 0; m < 2; ++m) a[m] = *(const bf16x8*)&Al[wr + m * 16 + lrow][lhi * 8];
        #pragma unroll
        for (int n = 0; n < 4; ++n) b[n] = *(const bf16x8*)&Bl[wc + n * 16 + lrow][lhi * 8];
        #pragma unroll
        for (int m = 0; m < 2; ++m)
            #pragma unroll
            for (int n = 0; n < 4; ++n)
                acc[m][n] = __builtin_amdgcn_mfma_f32_16x16x32_bf16(a[m], b[n], acc[m][n], 0, 0, 0);
        __syncthreads();
    }
    #pragma unroll
    for (int m = 0; m < 2; ++m) {
        int row0 = br * 64 + wr + m * 16 + (lhi << 2);
        #pragma unroll
        for (int n = 0; n < 4; ++n) {
            int col = wc + n * 16 + lrow;
            float bv = bias[col];
            if (!TRANS) {
                #pragma unroll
                for (int r = 0; r < 4; ++r)
                    out[(size_t)(row0 + r) * LAT + col] = f2bf(acc[m][n][r] + bv);
            } else {
                int batch = row0 >> 12, nb = row0 & 4095;
                union { unsigned short s[4]; unsigned long long q; } pk;
                #pragma unroll
                for (int r = 0; r < 4; ++r) pk.s[r] = f2bf(acc[m][n][r] + bv);
                *(unsigned long long*)&out[(size_t)batch * (LAT * NTOK) + (size_t)col * NTOK + nb] = pk.q;
            }
        }
    }
}

__global__ __launch_bounds__(256) void qp_kernel(const unsigned short* __restrict__ Kp,
                                                 const float* __restrict__ Wq,
                                                 const float* __restrict__ bq,
                                                 unsigned short* __restrict__ out) {
    __shared__ short Al[64][40];
    __shared__ short Bl[128][40];
    const int t = threadIdx.x, l = t & 63, w = t >> 6;
    const int br = blockIdx.x;
    const int wr = (w >> 1) * 32, wc = (w & 1) * 64;
    const int lrow = l & 15, lhi = l >> 4;
    f32x4 acc[2][4] = {};
    for (int k0 = 0; k0 < LAT; k0 += 32) {
        {
            int row = t >> 2, ch = t & 3;
            *(bf16x8*)&Al[row][ch * 8] =
                *(const bf16x8*)&Kp[(size_t)(br * 64 + row) * LAT + k0 + ch * 8];
        }
        #pragma unroll
        for (int j = 0; j < 4; ++j) {
            int c = t + j * 256, row = c >> 3, ch = c & 7;
            float4 v = *(const float4*)&Wq[(size_t)row * LAT + k0 + ch * 4];
            union { unsigned short s[4]; unsigned long long q; } pk;
            pk.s[0] = f2bf(v.x); pk.s[1] = f2bf(v.y); pk.s[2] = f2bf(v.z); pk.s[3] = f2bf(v.w);
            *(unsigned long long*)&Bl[row][ch * 4] = pk.q;
        }
        __syncthreads();
        bf16x8 a[2], b[4];
        #pragma unroll
        for (int m = 0; m < 2; ++m) a[m] = *(const bf16x8*)&Al[wr + m * 16 + lrow][lhi * 8];
        #pragma unroll
        for (int n = 0; n < 4; ++n) b[n] = *(const bf16x8*)&Bl[wc + n * 16 + lrow][lhi * 8];
        #pragma unroll
        for (int m = 0; m < 2; ++m)
            #pragma unroll
            for (int n = 0; n < 4; ++n)
                acc[m][n] = __builtin_amdgcn_mfma_f32_16x16x32_bf16(a[m], b[n], acc[m][n], 0, 0, 0);
        __syncthreads();
    }
    #pragma unroll
    for (int m = 0; m < 2; ++m) {
        int row0 = br * 64 + wr + m * 16 + (lhi << 2);
        #pragma unroll
        for (int n = 0; n < 4; ++n) {
            int col = wc + n * 16 + lrow;
            float bv = bq[col];
            #pragma unroll
            for (int r = 0; r < 4; ++r)
                out[(size_t)(row0 + r) * LAT + col] = f2bf(acc[m][n][r] + bv);
        }
    }
}

// ===========================================================================
extern "C" void kernel_launch(void* const* d_in, const int* in_sizes, int n_in,
                              void* d_out, int out_size, void* d_ws, size_t ws_size,
                              hipStream_t stream) {
    const float* Q  = (const float*)d_in[0];
    // d_in[1] (K) ignored by reference
    const float* V  = (const float*)d_in[2];
    const float* Wk = (const float*)d_in[3];
    const float* bk = (const float*)d_in[4];
    const float* Wq = (const float*)d_in[5];
    const float* bq = (const float*)d_in[6];
    const float* Wv = (const float*)d_in[7];
    const float* bv = (const float*)d_in[8];
    float* Y = (float*)d_out;

    char* ws = (char*)d_ws;
    unsigned short* Kp    = (unsigned short*)(ws);                         // 4 MB
    unsigned short* Qp    = (unsigned short*)(ws + 4194304);               // 4 MB
    unsigned short* VpT   = (unsigned short*)(ws + 8388608);               // 4 MB
    unsigned short* Wcomb = (unsigned short*)(ws + 12582912);              // 512 KB
    float*          bqk   = (float*)         (ws + 13107200);              // 512 B
    float2*         ml    = (float2*)        (ws + 13107712);              // 512 KB
    float*          Opart = (float*)         (ws + 13632000);              // 32 MB
    const size_t need_split = 13632000 + (size_t)SPLIT * MTOT * LAT * 4;   // ~45 MB

    if (ws_size >= need_split) {
        fuse_w<<<dim3(4, 128), 256, 0, stream>>>(Wq, Wk, bk, bq, Wcomb, bqk);
        proj_qk<<<dim3(512), 256, 0, stream>>>(Q, Wcomb, bk, bqk, Kp, Qp);
        proj_v<<<dim3(512), 256, 0, stream>>>(V, Wv, bv, VpT);
        attn_part<SPLIT><<<dim3(64, NB, SPLIT), 256, 0, stream>>>(Qp, Kp, VpT, Opart, ml);
        merge_k<<<dim3(MTOT / 8), 256, 0, stream>>>(Opart, ml, Y);
    } else {
        // proven round-1 pipeline + swizzled single-pass attention
        proj_kernel<false><<<dim3(256), 256, 0, stream>>>(Q, Wk, bk, Kp);
        proj_kernel<true ><<<dim3(256), 256, 0, stream>>>(V, Wv, bv, VpT);
        qp_kernel<<<dim3(256), 256, 0, stream>>>(Kp, Wq, bq, Qp);
        attn_part<1><<<dim3(64, NB, 1), 256, 0, stream>>>(Qp, Kp, VpT, Y, nullptr);
    }
}

// Round 3
// 220.276 us; speedup vs baseline: 1.3578x; 1.3374x over previous
//
#include <hip/hip_runtime.h>
#include <hip/hip_bf16.h>
#include <math.h>

// Problem constants
#define NB     4
#define NTOK   4096
#define IND    1024
#define LAT    128
#define MTOT   (NB*NTOK)
#define SPLIT  4
#define L2E    1.4426950408889634f
#define SC2    0.022542110013890053f   // (1/64) * log2(e), folded into Qp

typedef short bf16x8 __attribute__((ext_vector_type(8)));
typedef float f32x4  __attribute__((ext_vector_type(4)));
typedef float f32x16 __attribute__((ext_vector_type(16)));

__device__ __forceinline__ unsigned short f2bf(float x) {
    union { float f; unsigned int u; } v; v.f = x;
    unsigned int r = v.u + 0x7FFFu + ((v.u >> 16) & 1u);  // RNE
    return (unsigned short)(r >> 16);
}
__device__ __forceinline__ float bf2f(unsigned short b) {
    union { unsigned int u; float f; } v; v.u = ((unsigned int)b) << 16;
    return v.f;
}
__device__ __forceinline__ unsigned cvtpk(float lo, float hi) {
    unsigned r;
    asm("v_cvt_pk_bf16_f32 %0, %1, %2" : "=v"(r) : "v"(lo), "v"(hi));
    return r;
}
// v_permlane32_swap_b32: x.hi32lanes <-> y.lo32lanes
__device__ __forceinline__ void permswap(unsigned &x, unsigned &y) {
    asm volatile("v_permlane32_swap_b32 %0, %1" : "+v"(x), "+v"(y));
}

// ===========================================================================
// fuse_w: Wcomb rows 0..127 = bf16(Wk); rows 128..255 = bf16(SC2 * Wq@Wk);
// bqk = SC2 * (Wq@bk + bq). grid (4,128) x 256.
// ===========================================================================
__global__ __launch_bounds__(256) void fuse_w(const float* __restrict__ Wq,
                                              const float* __restrict__ Wk,
                                              const float* __restrict__ bk,
                                              const float* __restrict__ bq,
                                              unsigned short* __restrict__ Wcomb,
                                              float* __restrict__ bqk) {
    const int o = blockIdx.y;                       // 0..127
    const int i = blockIdx.x * 256 + threadIdx.x;   // 0..1023
    Wcomb[(size_t)o * IND + i] = f2bf(Wk[(size_t)o * IND + i]);
    float acc = 0.f;
    #pragma unroll 8
    for (int l = 0; l < 128; ++l)
        acc = fmaf(Wq[o * 128 + l], Wk[(size_t)l * IND + i], acc);
    Wcomb[(size_t)(128 + o) * IND + i] = f2bf(acc * SC2);
    if (blockIdx.x == 0 && threadIdx.x == 0) {
        float b = bq[o];
        for (int l = 0; l < 128; ++l) b = fmaf(Wq[o * 128 + l], bk[l], b);
        bqk[o] = b * SC2;
    }
}

// ===========================================================================
// proj_qk: [Kp | Qp] = Q @ [Wk | Wqk]^T + [bk | bqk].  BM=32, BN=256, BK=64.
// 512 blocks x 256 thr. (unchanged from round 2 — proven)
// ===========================================================================
__global__ __launch_bounds__(256) void proj_qk(const float* __restrict__ X,
                                               const unsigned short* __restrict__ Wcomb,
                                               const float* __restrict__ bk,
                                               const float* __restrict__ bqk,
                                               unsigned short* __restrict__ Kp,
                                               unsigned short* __restrict__ Qp) {
    __shared__ __align__(16) char lds[4096 + 32768];
    const int t = threadIdx.x, l = t & 63, w = t >> 6;
    const int br = blockIdx.x;
    const int lrow = l & 15, lhi = l >> 4;
    const int wr = (w >> 1) * 16, wc = (w & 1) * 128;

    f32x4 acc[8] = {};

    for (int k0 = 0; k0 < IND; k0 += 64) {
        #pragma unroll
        for (int j = 0; j < 2; ++j) {   // A: 32x64 f32 -> bf16
            int c = t + j * 256, row = c >> 4, ch = c & 15;
            float4 v = *(const float4*)&X[(size_t)(br * 32 + row) * IND + k0 + ch * 4];
            union { unsigned short s[4]; unsigned long long q; } pk;
            pk.s[0] = f2bf(v.x); pk.s[1] = f2bf(v.y);
            pk.s[2] = f2bf(v.z); pk.s[3] = f2bf(v.w);
            *(unsigned long long*)(lds + ((row * 128 + ch * 8) ^ ((row & 7) << 4))) = pk.q;
        }
        #pragma unroll
        for (int j = 0; j < 8; ++j) {   // B: 256x64 bf16
            int c = t + j * 256, row = c >> 3, ch = c & 7;
            *(bf16x8*)(lds + 4096 + ((row * 128 + ch * 16) ^ ((row & 7) << 4))) =
                *(const bf16x8*)&Wcomb[(size_t)row * IND + k0 + ch * 8];
        }
        __syncthreads();

        const int arow = wr + lrow;
        bf16x8 a[2];
        #pragma unroll
        for (int kk = 0; kk < 2; ++kk)
            a[kk] = *(const bf16x8*)(lds + ((arow * 128 + kk * 64 + lhi * 16) ^ ((arow & 7) << 4)));
        #pragma unroll
        for (int n = 0; n < 8; ++n) {
            const int brow = wc + n * 16 + lrow;
            #pragma unroll
            for (int kk = 0; kk < 2; ++kk) {
                bf16x8 b = *(const bf16x8*)(lds + 4096 +
                    ((brow * 128 + kk * 64 + lhi * 16) ^ ((brow & 7) << 4)));
                acc[n] = __builtin_amdgcn_mfma_f32_16x16x32_bf16(a[kk], b, acc[n], 0, 0, 0);
            }
        }
        __syncthreads();
    }

    const int row0 = br * 32 + wr + lhi * 4;
    unsigned short* out = (wc == 0) ? Kp : Qp;
    const float* bias = (wc == 0) ? bk : bqk;
    #pragma unroll
    for (int n = 0; n < 8; ++n) {
        int col = n * 16 + lrow;
        float bv = bias[col];
        #pragma unroll
        for (int r = 0; r < 4; ++r)
            out[(size_t)(row0 + r) * LAT + col] = f2bf(acc[n][r] + bv);
    }
}

// ===========================================================================
// proj_v: VpT[b][d][n] = (V @ Wv^T + bv)^T.  (unchanged from round 2)
// ===========================================================================
__global__ __launch_bounds__(256) void proj_v(const float* __restrict__ X,
                                              const float* __restrict__ Wv,
                                              const float* __restrict__ bv,
                                              unsigned short* __restrict__ VpT) {
    __shared__ __align__(16) char lds[4096 + 16384];
    const int t = threadIdx.x, l = t & 63, w = t >> 6;
    const int br = blockIdx.x;
    const int lrow = l & 15, lhi = l >> 4;
    const int wr = (w >> 1) * 16, wc = (w & 1) * 64;

    f32x4 acc[4] = {};

    for (int k0 = 0; k0 < IND; k0 += 64) {
        #pragma unroll
        for (int j = 0; j < 2; ++j) {
            int c = t + j * 256, row = c >> 4, ch = c & 15;
            float4 v = *(const float4*)&X[(size_t)(br * 32 + row) * IND + k0 + ch * 4];
            union { unsigned short s[4]; unsigned long long q; } pk;
            pk.s[0] = f2bf(v.x); pk.s[1] = f2bf(v.y);
            pk.s[2] = f2bf(v.z); pk.s[3] = f2bf(v.w);
            *(unsigned long long*)(lds + ((row * 128 + ch * 8) ^ ((row & 7) << 4))) = pk.q;
        }
        #pragma unroll
        for (int j = 0; j < 8; ++j) {
            int c = t + j * 256, row = c >> 4, ch = c & 15;
            float4 v = *(const float4*)&Wv[(size_t)row * IND + k0 + ch * 4];
            union { unsigned short s[4]; unsigned long long q; } pk;
            pk.s[0] = f2bf(v.x); pk.s[1] = f2bf(v.y);
            pk.s[2] = f2bf(v.z); pk.s[3] = f2bf(v.w);
            *(unsigned long long*)(lds + 4096 + ((row * 128 + ch * 8) ^ ((row & 7) << 4))) = pk.q;
        }
        __syncthreads();

        const int arow = wr + lrow;
        bf16x8 a[2];
        #pragma unroll
        for (int kk = 0; kk < 2; ++kk)
            a[kk] = *(const bf16x8*)(lds + ((arow * 128 + kk * 64 + lhi * 16) ^ ((arow & 7) << 4)));
        #pragma unroll
        for (int n = 0; n < 4; ++n) {
            const int brow = wc + n * 16 + lrow;
            #pragma unroll
            for (int kk = 0; kk < 2; ++kk) {
                bf16x8 b = *(const bf16x8*)(lds + 4096 +
                    ((brow * 128 + kk * 64 + lhi * 16) ^ ((brow & 7) << 4)));
                acc[n] = __builtin_amdgcn_mfma_f32_16x16x32_bf16(a[kk], b, acc[n], 0, 0, 0);
            }
        }
        __syncthreads();
    }

    const int row0 = br * 32 + wr + lhi * 4;
    const int batch = row0 >> 12, tok = row0 & 4095;
    #pragma unroll
    for (int n = 0; n < 4; ++n) {
        int col = wc + n * 16 + lrow;
        float bv_ = bv[col];
        union { unsigned short s[4]; unsigned long long q; } pk;
        #pragma unroll
        for (int r = 0; r < 4; ++r) pk.s[r] = f2bf(acc[n][r] + bv_);
        *(unsigned long long*)&VpT[(size_t)batch * (LAT * NTOK) + (size_t)col * NTOK + tok] = pk.q;
    }
}

// ===========================================================================
// attn2<NSPLIT>: swapped-operand flash attention, 32x32x16 MFMA.
// Block = 4 waves x 32 q-rows = 128 q. KV tile 64. Q pre-scaled (exp2 domain).
// S^T = mfma(K,Q): lane-local softmax rows. P in-register via cvt_pk+permlane.
// O^T = mfma(V^T, P^T). NSPLIT>1: bf16 partials + (m,l); else normalized f32 Y.
// ===========================================================================
template<int NSPLIT>
__global__ __launch_bounds__(256) void attn2(const unsigned short* __restrict__ Qp,
                                             const unsigned short* __restrict__ Kp,
                                             const unsigned short* __restrict__ VpT,
                                             unsigned short* __restrict__ Opart,
                                             float2* __restrict__ ml,
                                             float* __restrict__ Y) {
    __shared__ __align__(16) char ldsK[16384];   // K [64 k][128 d] bf16, swizzled
    __shared__ __align__(16) char ldsV[16384];   // VT [128 d][64 k] bf16, swizzled
    const int t = threadIdx.x, l = t & 63, w = t >> 6;
    const int lane31 = l & 31, hi = l >> 5;

    // block decode (XCD-grouped for NSPLIT==4: same (b,ck) -> same XCD L2)
    int qt, b, ck;
    if constexpr (NSPLIT == 4) {
        int x = blockIdx.x;
        int glo = x & 7, rest = x >> 3;
        qt = rest & 31;
        int g = glo + 8 * (rest >> 5);   // 0..15
        b = g >> 2; ck = g & 3;
    } else {
        qt = blockIdx.x & 31; b = blockIdx.x >> 5; ck = 0;
    }
    const size_t base  = (size_t)b * ((size_t)NTOK * LAT);
    const size_t vbase = (size_t)b * ((size_t)LAT * NTOK);
    const int wq = qt * 128 + w * 32;
    const int k_base = ck * (NTOK / NSPLIT);
    const int kts = (NTOK / NSPLIT) / 64;

    // Q fragments (B-operand): lane holds Q[wq+lane31][ds*16 + hi*8 .. +8]
    bf16x8 qf[8];
    {
        const size_t qrow = base + (size_t)(wq + lane31) * LAT;
        #pragma unroll
        for (int ds = 0; ds < 8; ++ds)
            qf[ds] = *(const bf16x8*)&Qp[qrow + ds * 16 + hi * 8];
    }

    f32x16 OA[4] = {};           // O^T accum: rows d (4 blocks of 32), col q=lane31
    float mrun = -1e30f, lrun = 0.f;

    // register prefetch of KV tile
    bf16x8 stg[8];
    {
        const int k_lo = k_base;
        #pragma unroll
        for (int j = 0; j < 4; ++j) {
            int c = t + j * 256, row = c >> 4, ch = c & 15;
            stg[j] = *(const bf16x8*)&Kp[base + (size_t)(k_lo + row) * LAT + ch * 8];
        }
        #pragma unroll
        for (int j = 0; j < 4; ++j) {
            int c = t + j * 256, row = c >> 3, ch = c & 7;
            stg[4 + j] = *(const bf16x8*)&VpT[vbase + (size_t)row * NTOK + k_lo + ch * 8];
        }
    }

    for (int kt = 0; kt < kts; ++kt) {
        // write staged tile to LDS (swizzled)
        #pragma unroll
        for (int j = 0; j < 4; ++j) {
            int c = t + j * 256, row = c >> 4, ch = c & 15;
            *(bf16x8*)(ldsK + ((row * 256 + ch * 16) ^ ((row & 7) << 4))) = stg[j];
        }
        #pragma unroll
        for (int j = 0; j < 4; ++j) {
            int c = t + j * 256, row = c >> 3, ch = c & 7;
            *(bf16x8*)(ldsV + ((row * 128 + ch * 16) ^ ((row & 7) << 4))) = stg[4 + j];
        }
        // prefetch next tile (overlaps with compute below)
        if (kt + 1 < kts) {
            const int k_lo = k_base + (kt + 1) * 64;
            #pragma unroll
            for (int j = 0; j < 4; ++j) {
                int c = t + j * 256, row = c >> 4, ch = c & 15;
                stg[j] = *(const bf16x8*)&Kp[base + (size_t)(k_lo + row) * LAT + ch * 8];
            }
            #pragma unroll
            for (int j = 0; j < 4; ++j) {
                int c = t + j * 256, row = c >> 3, ch = c & 7;
                stg[4 + j] = *(const bf16x8*)&VpT[vbase + (size_t)row * NTOK + k_lo + ch * 8];
            }
        }
        __syncthreads();

        // S^T = K * Q^T : D[k][q], col=lane31=q, row k = kb*32+(reg&3)+8*(reg>>2)+4*hi
        f32x16 SA[2];
        #pragma unroll
        for (int kb = 0; kb < 2; ++kb) {
            f32x16 s = {};
            const int kr = kb * 32 + lane31;
            #pragma unroll
            for (int ds = 0; ds < 8; ++ds) {
                bf16x8 kf = *(const bf16x8*)(ldsK +
                    ((kr * 256 + ds * 32 + hi * 16) ^ ((kr & 7) << 4)));
                s = __builtin_amdgcn_mfma_f32_32x32x16_bf16(kf, qf[ds], s, 0, 0, 0);
            }
            SA[kb] = s;
        }

        // lane-local softmax (this lane's q = wq+lane31; partner lane l^32 has
        // the other 16 k-rows of the same q per kb)
        float pmax = -1e30f;
        #pragma unroll
        for (int kb = 0; kb < 2; ++kb)
            #pragma unroll
            for (int r = 0; r < 16; ++r) pmax = fmaxf(pmax, SA[kb][r]);
        pmax = fmaxf(pmax, __shfl_xor(pmax, 32));

        if (__any(pmax > mrun + 8.f)) {      // defer-max (T13)
            float mnew = fmaxf(mrun, pmax);
            float al = exp2f(mrun - mnew);
            mrun = mnew;
            lrun *= al;
            #pragma unroll
            for (int db = 0; db < 4; ++db)
                #pragma unroll
                for (int r = 0; r < 16; ++r) OA[db][r] *= al;
        }

        float ls = 0.f;
        #pragma unroll
        for (int kb = 0; kb < 2; ++kb) {
            float p[16];
            #pragma unroll
            for (int r = 0; r < 16; ++r) {
                p[r] = exp2f(SA[kb][r] - mrun);
                ls += p[r];
            }
            // build P^T B-frags (k-slices kb*2+0, kb*2+1) in-register
            unsigned a0 = cvtpk(p[0], p[1]),  a1 = cvtpk(p[2], p[3]);
            unsigned a2 = cvtpk(p[4], p[5]),  a3 = cvtpk(p[6], p[7]);
            permswap(a0, a2); permswap(a1, a3);
            unsigned b0 = cvtpk(p[8], p[9]),   b1 = cvtpk(p[10], p[11]);
            unsigned b2 = cvtpk(p[12], p[13]), b3 = cvtpk(p[14], p[15]);
            permswap(b0, b2); permswap(b1, b3);
            union { unsigned u[4]; bf16x8 v; } f0 = {{a0, a1, a2, a3}};
            union { unsigned u[4]; bf16x8 v; } f1 = {{b0, b1, b2, b3}};

            // O^T += V^T * P^T
            #pragma unroll
            for (int db = 0; db < 4; ++db) {
                const int d = db * 32 + lane31;
                bf16x8 vfA = *(const bf16x8*)(ldsV +
                    ((d * 128 + (kb * 2 + 0) * 32 + hi * 16) ^ ((d & 7) << 4)));
                OA[db] = __builtin_amdgcn_mfma_f32_32x32x16_bf16(vfA, f0.v, OA[db], 0, 0, 0);
                bf16x8 vfB = *(const bf16x8*)(ldsV +
                    ((d * 128 + (kb * 2 + 1) * 32 + hi * 16) ^ ((d & 7) << 4)));
                OA[db] = __builtin_amdgcn_mfma_f32_32x32x16_bf16(vfB, f1.v, OA[db], 0, 0, 0);
            }
        }
        ls += __shfl_xor(ls, 32);
        lrun += ls;
        __syncthreads();
    }

    // epilogue: lane writes its q-row (= wq+lane31); d = db*32 + 8*g + 4*hi + j
    if constexpr (NSPLIT == 1) {
        const float inv = 1.0f / lrun;
        float* dst = &Y[base + (size_t)(wq + lane31) * LAT];
        #pragma unroll
        for (int db = 0; db < 4; ++db)
            #pragma unroll
            for (int g = 0; g < 4; ++g) {
                f32x4 v;
                #pragma unroll
                for (int j = 0; j < 4; ++j) v[j] = OA[db][4 * g + j] * inv;
                *(f32x4*)&dst[db * 32 + 8 * g + 4 * hi] = v;
            }
    } else {
        const size_t prow = (size_t)ck * MTOT + (size_t)b * NTOK + wq + lane31;
        unsigned short* dst = &Opart[prow * LAT];
        #pragma unroll
        for (int db = 0; db < 4; ++db)
            #pragma unroll
            for (int g = 0; g < 4; ++g) {
                union { unsigned short s[4]; unsigned long long q; } pk;
                #pragma unroll
                for (int j = 0; j < 4; ++j) pk.s[j] = f2bf(OA[db][4 * g + j]);
                *(unsigned long long*)&dst[db * 32 + 8 * g + 4 * hi] = pk.q;
            }
        if (l < 32) ml[prow] = make_float2(mrun, lrun);
    }
}

// ===========================================================================
// merge2: Y = (sum_c 2^{m_c-M} O_c) / (sum_c 2^{m_c-M} l_c). bf16 partials.
// grid 1024 x 256: 16 threads/row, 8 cols each.
// ===========================================================================
__global__ __launch_bounds__(256) void merge2(const unsigned short* __restrict__ Opart,
                                              const float2* __restrict__ ml,
                                              float* __restrict__ Y) {
    const int idx = blockIdx.x * 256 + threadIdx.x;
    const int row = idx >> 4, cc = (idx & 15) * 8;
    float m[SPLIT], li[SPLIT];
    float M = -1e30f;
    #pragma unroll
    for (int c = 0; c < SPLIT; ++c) {
        float2 p = ml[(size_t)c * MTOT + row];
        m[c] = p.x; li[c] = p.y; M = fmaxf(M, m[c]);
    }
    float L = 0.f, wg[SPLIT];
    #pragma unroll
    for (int c = 0; c < SPLIT; ++c) { wg[c] = exp2f(m[c] - M); L += wg[c] * li[c]; }
    float acc[8] = {};
    #pragma unroll
    for (int c = 0; c < SPLIT; ++c) {
        bf16x8 v = *(const bf16x8*)&Opart[((size_t)c * MTOT + row) * LAT + cc];
        #pragma unroll
        for (int j = 0; j < 8; ++j)
            acc[j] += wg[c] * bf2f((unsigned short)v[j]);
    }
    const float inv = 1.f / L;
    f32x4 o0, o1;
    #pragma unroll
    for (int j = 0; j < 4; ++j) { o0[j] = acc[j] * inv; o1[j] = acc[4 + j] * inv; }
    *(f32x4*)&Y[(size_t)row * LAT + cc] = o0;
    *(f32x4*)&Y[(size_t)row * LAT + cc + 4] = o1;
}

// ===========================================================================
extern "C" void kernel_launch(void* const* d_in, const int* in_sizes, int n_in,
                              void* d_out, int out_size, void* d_ws, size_t ws_size,
                              hipStream_t stream) {
    const float* Q  = (const float*)d_in[0];
    // d_in[1] (K) ignored by reference
    const float* V  = (const float*)d_in[2];
    const float* Wk = (const float*)d_in[3];
    const float* bk = (const float*)d_in[4];
    const float* Wq = (const float*)d_in[5];
    const float* bq = (const float*)d_in[6];
    const float* Wv = (const float*)d_in[7];
    const float* bv = (const float*)d_in[8];
    float* Y = (float*)d_out;

    char* ws = (char*)d_ws;
    unsigned short* Kp    = (unsigned short*)(ws);                 // 4 MB
    unsigned short* Qp    = (unsigned short*)(ws + (4 << 20));     // 4 MB
    unsigned short* VpT   = (unsigned short*)(ws + (8 << 20));     // 4 MB
    unsigned short* Wcomb = (unsigned short*)(ws + (12 << 20));    // 512 KB
    float*          bqk   = (float*)         (ws + 13107200);      // 512 B
    float2*         ml    = (float2*)        (ws + 13107712);      // 512 KB
    unsigned short* Opart = (unsigned short*)(ws + 13632000);      // 16 MB
    const size_t need_split = 13632000 + (size_t)SPLIT * MTOT * LAT * 2;

    fuse_w<<<dim3(4, 128), 256, 0, stream>>>(Wq, Wk, bk, bq, Wcomb, bqk);
    proj_qk<<<dim3(512), 256, 0, stream>>>(Q, Wcomb, bk, bqk, Kp, Qp);
    proj_v<<<dim3(512), 256, 0, stream>>>(V, Wv, bv, VpT);

    if (ws_size >= need_split) {
        attn2<SPLIT><<<dim3(32 * NB * SPLIT), 256, 0, stream>>>(Qp, Kp, VpT, Opart, ml, nullptr);
        merge2<<<dim3(MTOT * 16 / 256), 256, 0, stream>>>(Opart, ml, Y);
    } else {
        attn2<1><<<dim3(32 * NB), 256, 0, stream>>>(Qp, Kp, VpT, nullptr, nullptr, Y);
    }
}

// Round 4
// 138.669 us; speedup vs baseline: 2.1569x; 1.5885x over previous
//
#include <hip/hip_runtime.h>
#include <hip/hip_bf16.h>
#include <math.h>

// Problem constants
#define NB     4
#define NTOK   4096
#define IND    1024
#define LAT    128
#define MTOT   (NB*NTOK)
#define SPLIT  4
#define L2E    1.4426950408889634f
#define SC2    0.022542110013890053f   // (1/64) * log2(e), folded into Qp

typedef short bf16x8 __attribute__((ext_vector_type(8)));
typedef float f32x4  __attribute__((ext_vector_type(4)));
typedef float f32x16 __attribute__((ext_vector_type(16)));

__device__ __forceinline__ unsigned short f2bf(float x) {
    union { float f; unsigned int u; } v; v.f = x;
    unsigned int r = v.u + 0x7FFFu + ((v.u >> 16) & 1u);  // RNE
    return (unsigned short)(r >> 16);
}
__device__ __forceinline__ float bf2f(unsigned short b) {
    union { unsigned int u; float f; } v; v.u = ((unsigned int)b) << 16;
    return v.f;
}
__device__ __forceinline__ unsigned cvtpk(float lo, float hi) {
    unsigned r;
    asm("v_cvt_pk_bf16_f32 %0, %1, %2" : "=v"(r) : "v"(lo), "v"(hi));
    return r;
}
// v_permlane32_swap_b32: x.hi32lanes <-> y.lo32lanes
__device__ __forceinline__ void permswap(unsigned &x, unsigned &y) {
    asm volatile("v_permlane32_swap_b32 %0, %1" : "+v"(x), "+v"(y));
}

// ===========================================================================
// fuse_w: Wcomb rows 0..127 = bf16(Wk); rows 128..255 = bf16(SC2 * Wq@Wk);
// bqk = SC2 * (Wq@bk + bq). grid (4,128) x 256.
// ===========================================================================
__global__ __launch_bounds__(256) void fuse_w(const float* __restrict__ Wq,
                                              const float* __restrict__ Wk,
                                              const float* __restrict__ bk,
                                              const float* __restrict__ bq,
                                              unsigned short* __restrict__ Wcomb,
                                              float* __restrict__ bqk) {
    const int o = blockIdx.y;                       // 0..127
    const int i = blockIdx.x * 256 + threadIdx.x;   // 0..1023
    Wcomb[(size_t)o * IND + i] = f2bf(Wk[(size_t)o * IND + i]);
    float acc = 0.f;
    #pragma unroll 8
    for (int l = 0; l < 128; ++l)
        acc = fmaf(Wq[o * 128 + l], Wk[(size_t)l * IND + i], acc);
    Wcomb[(size_t)(128 + o) * IND + i] = f2bf(acc * SC2);
    if (blockIdx.x == 0 && threadIdx.x == 0) {
        float b = bq[o];
        for (int l = 0; l < 128; ++l) b = fmaf(Wq[o * 128 + l], bk[l], b);
        bqk[o] = b * SC2;
    }
}

// ===========================================================================
// proj_qk: [Kp | Qp] = Q @ [Wk | Wqk]^T + [bk | bqk].  BM=32, BN=256, BK=64.
// 512 blocks x 256 thr. Register-prefetch double buffer: next tile's global
// loads are issued before compute so they fly under the MFMAs.
// __launch_bounds__(256,2) -> VGPR cap 256: all staging loads stay in flight.
// ===========================================================================
__global__ __launch_bounds__(256, 2) void proj_qk(const float* __restrict__ X,
                                                  const unsigned short* __restrict__ Wcomb,
                                                  const float* __restrict__ bk,
                                                  const float* __restrict__ bqk,
                                                  unsigned short* __restrict__ Kp,
                                                  unsigned short* __restrict__ Qp) {
    __shared__ __align__(16) char lds[4096 + 32768];
    const int t = threadIdx.x, l = t & 63, w = t >> 6;
    const int br = blockIdx.x;
    const int lrow = l & 15, lhi = l >> 4;
    const int wr = (w >> 1) * 16, wc = (w & 1) * 128;

    // staging index precompute
    const int arow0 = t >> 4, ach = t & 15;          // A chunk j: row arow0 + j*16? no: c = t + j*256
    f32x4 acc[8] = {};

    float4 aR[2];
    bf16x8 bR[8];
    // initial load (k0 = 0)
    #pragma unroll
    for (int j = 0; j < 2; ++j) {
        int c = t + j * 256, row = c >> 4, ch = c & 15;
        aR[j] = *(const float4*)&X[(size_t)(br * 32 + row) * IND + ch * 4];
    }
    #pragma unroll
    for (int j = 0; j < 8; ++j) {
        int c = t + j * 256, row = c >> 3, ch = c & 7;
        bR[j] = *(const bf16x8*)&Wcomb[(size_t)row * IND + ch * 8];
    }

    for (int k0 = 0; k0 < IND; k0 += 64) {
        // write staged regs to LDS
        #pragma unroll
        for (int j = 0; j < 2; ++j) {
            int c = t + j * 256, row = c >> 4, ch = c & 15;
            union { unsigned short s[4]; unsigned long long q; } pk;
            pk.s[0] = f2bf(aR[j].x); pk.s[1] = f2bf(aR[j].y);
            pk.s[2] = f2bf(aR[j].z); pk.s[3] = f2bf(aR[j].w);
            *(unsigned long long*)(lds + ((row * 128 + ch * 8) ^ ((row & 7) << 4))) = pk.q;
        }
        #pragma unroll
        for (int j = 0; j < 8; ++j) {
            int c = t + j * 256, row = c >> 3, ch = c & 7;
            *(bf16x8*)(lds + 4096 + ((row * 128 + ch * 16) ^ ((row & 7) << 4))) = bR[j];
        }
        // issue next tile's loads (fly under compute)
        if (k0 + 64 < IND) {
            #pragma unroll
            for (int j = 0; j < 2; ++j) {
                int c = t + j * 256, row = c >> 4, ch = c & 15;
                aR[j] = *(const float4*)&X[(size_t)(br * 32 + row) * IND + k0 + 64 + ch * 4];
            }
            #pragma unroll
            for (int j = 0; j < 8; ++j) {
                int c = t + j * 256, row = c >> 3, ch = c & 7;
                bR[j] = *(const bf16x8*)&Wcomb[(size_t)row * IND + k0 + 64 + ch * 8];
            }
        }
        __syncthreads();

        const int arow = wr + lrow;
        bf16x8 a[2];
        #pragma unroll
        for (int kk = 0; kk < 2; ++kk)
            a[kk] = *(const bf16x8*)(lds + ((arow * 128 + kk * 64 + lhi * 16) ^ ((arow & 7) << 4)));
        #pragma unroll
        for (int n = 0; n < 8; ++n) {
            const int brow = wc + n * 16 + lrow;
            #pragma unroll
            for (int kk = 0; kk < 2; ++kk) {
                bf16x8 b = *(const bf16x8*)(lds + 4096 +
                    ((brow * 128 + kk * 64 + lhi * 16) ^ ((brow & 7) << 4)));
                acc[n] = __builtin_amdgcn_mfma_f32_16x16x32_bf16(a[kk], b, acc[n], 0, 0, 0);
            }
        }
        __syncthreads();
    }
    (void)arow0; (void)ach;

    const int row0 = br * 32 + wr + lhi * 4;
    unsigned short* out = (wc == 0) ? Kp : Qp;
    const float* bias = (wc == 0) ? bk : bqk;
    #pragma unroll
    for (int n = 0; n < 8; ++n) {
        int col = n * 16 + lrow;
        float bv = bias[col];
        #pragma unroll
        for (int r = 0; r < 4; ++r)
            out[(size_t)(row0 + r) * LAT + col] = f2bf(acc[n][r] + bv);
    }
}

// ===========================================================================
// proj_v: VpT[b][d][n] = (V @ Wv^T + bv)^T.  Same register-prefetch structure.
// ===========================================================================
__global__ __launch_bounds__(256, 2) void proj_v(const float* __restrict__ X,
                                                 const float* __restrict__ Wv,
                                                 const float* __restrict__ bv,
                                                 unsigned short* __restrict__ VpT) {
    __shared__ __align__(16) char lds[4096 + 16384];
    const int t = threadIdx.x, l = t & 63, w = t >> 6;
    const int br = blockIdx.x;
    const int lrow = l & 15, lhi = l >> 4;
    const int wr = (w >> 1) * 16, wc = (w & 1) * 64;

    f32x4 acc[4] = {};

    float4 aR[2], bR[8];
    #pragma unroll
    for (int j = 0; j < 2; ++j) {
        int c = t + j * 256, row = c >> 4, ch = c & 15;
        aR[j] = *(const float4*)&X[(size_t)(br * 32 + row) * IND + ch * 4];
    }
    #pragma unroll
    for (int j = 0; j < 8; ++j) {
        int c = t + j * 256, row = c >> 4, ch = c & 15;
        bR[j] = *(const float4*)&Wv[(size_t)row * IND + ch * 4];
    }

    for (int k0 = 0; k0 < IND; k0 += 64) {
        #pragma unroll
        for (int j = 0; j < 2; ++j) {
            int c = t + j * 256, row = c >> 4, ch = c & 15;
            union { unsigned short s[4]; unsigned long long q; } pk;
            pk.s[0] = f2bf(aR[j].x); pk.s[1] = f2bf(aR[j].y);
            pk.s[2] = f2bf(aR[j].z); pk.s[3] = f2bf(aR[j].w);
            *(unsigned long long*)(lds + ((row * 128 + ch * 8) ^ ((row & 7) << 4))) = pk.q;
        }
        #pragma unroll
        for (int j = 0; j < 8; ++j) {
            int c = t + j * 256, row = c >> 4, ch = c & 15;
            union { unsigned short s[4]; unsigned long long q; } pk;
            pk.s[0] = f2bf(bR[j].x); pk.s[1] = f2bf(bR[j].y);
            pk.s[2] = f2bf(bR[j].z); pk.s[3] = f2bf(bR[j].w);
            *(unsigned long long*)(lds + 4096 + ((row * 128 + ch * 8) ^ ((row & 7) << 4))) = pk.q;
        }
        if (k0 + 64 < IND) {
            #pragma unroll
            for (int j = 0; j < 2; ++j) {
                int c = t + j * 256, row = c >> 4, ch = c & 15;
                aR[j] = *(const float4*)&X[(size_t)(br * 32 + row) * IND + k0 + 64 + ch * 4];
            }
            #pragma unroll
            for (int j = 0; j < 8; ++j) {
                int c = t + j * 256, row = c >> 4, ch = c & 15;
                bR[j] = *(const float4*)&Wv[(size_t)row * IND + k0 + 64 + ch * 4];
            }
        }
        __syncthreads();

        const int arow = wr + lrow;
        bf16x8 a[2];
        #pragma unroll
        for (int kk = 0; kk < 2; ++kk)
            a[kk] = *(const bf16x8*)(lds + ((arow * 128 + kk * 64 + lhi * 16) ^ ((arow & 7) << 4)));
        #pragma unroll
        for (int n = 0; n < 4; ++n) {
            const int brow = wc + n * 16 + lrow;
            #pragma unroll
            for (int kk = 0; kk < 2; ++kk) {
                bf16x8 b = *(const bf16x8*)(lds + 4096 +
                    ((brow * 128 + kk * 64 + lhi * 16) ^ ((brow & 7) << 4)));
                acc[n] = __builtin_amdgcn_mfma_f32_16x16x32_bf16(a[kk], b, acc[n], 0, 0, 0);
            }
        }
        __syncthreads();
    }

    const int row0 = br * 32 + wr + lhi * 4;
    const int batch = row0 >> 12, tok = row0 & 4095;
    #pragma unroll
    for (int n = 0; n < 4; ++n) {
        int col = wc + n * 16 + lrow;
        float bv_ = bv[col];
        union { unsigned short s[4]; unsigned long long q; } pk;
        #pragma unroll
        for (int r = 0; r < 4; ++r) pk.s[r] = f2bf(acc[n][r] + bv_);
        *(unsigned long long*)&VpT[(size_t)batch * (LAT * NTOK) + (size_t)col * NTOK + tok] = pk.q;
    }
}

// ===========================================================================
// attn2<NSPLIT>: swapped-operand flash attention, 32x32x16 MFMA. (unchanged)
// ===========================================================================
template<int NSPLIT>
__global__ __launch_bounds__(256) void attn2(const unsigned short* __restrict__ Qp,
                                             const unsigned short* __restrict__ Kp,
                                             const unsigned short* __restrict__ VpT,
                                             unsigned short* __restrict__ Opart,
                                             float2* __restrict__ ml,
                                             float* __restrict__ Y) {
    __shared__ __align__(16) char ldsK[16384];   // K [64 k][128 d] bf16, swizzled
    __shared__ __align__(16) char ldsV[16384];   // VT [128 d][64 k] bf16, swizzled
    const int t = threadIdx.x, l = t & 63, w = t >> 6;
    const int lane31 = l & 31, hi = l >> 5;

    int qt, b, ck;
    if constexpr (NSPLIT == 4) {
        int x = blockIdx.x;
        int glo = x & 7, rest = x >> 3;
        qt = rest & 31;
        int g = glo + 8 * (rest >> 5);   // 0..15
        b = g >> 2; ck = g & 3;
    } else {
        qt = blockIdx.x & 31; b = blockIdx.x >> 5; ck = 0;
    }
    const size_t base  = (size_t)b * ((size_t)NTOK * LAT);
    const size_t vbase = (size_t)b * ((size_t)LAT * NTOK);
    const int wq = qt * 128 + w * 32;
    const int k_base = ck * (NTOK / NSPLIT);
    const int kts = (NTOK / NSPLIT) / 64;

    bf16x8 qf[8];
    {
        const size_t qrow = base + (size_t)(wq + lane31) * LAT;
        #pragma unroll
        for (int ds = 0; ds < 8; ++ds)
            qf[ds] = *(const bf16x8*)&Qp[qrow + ds * 16 + hi * 8];
    }

    f32x16 OA[4] = {};
    float mrun = -1e30f, lrun = 0.f;

    bf16x8 stg[8];
    {
        const int k_lo = k_base;
        #pragma unroll
        for (int j = 0; j < 4; ++j) {
            int c = t + j * 256, row = c >> 4, ch = c & 15;
            stg[j] = *(const bf16x8*)&Kp[base + (size_t)(k_lo + row) * LAT + ch * 8];
        }
        #pragma unroll
        for (int j = 0; j < 4; ++j) {
            int c = t + j * 256, row = c >> 3, ch = c & 7;
            stg[4 + j] = *(const bf16x8*)&VpT[vbase + (size_t)row * NTOK + k_lo + ch * 8];
        }
    }

    for (int kt = 0; kt < kts; ++kt) {
        #pragma unroll
        for (int j = 0; j < 4; ++j) {
            int c = t + j * 256, row = c >> 4, ch = c & 15;
            *(bf16x8*)(ldsK + ((row * 256 + ch * 16) ^ ((row & 7) << 4))) = stg[j];
        }
        #pragma unroll
        for (int j = 0; j < 4; ++j) {
            int c = t + j * 256, row = c >> 3, ch = c & 7;
            *(bf16x8*)(ldsV + ((row * 128 + ch * 16) ^ ((row & 7) << 4))) = stg[4 + j];
        }
        if (kt + 1 < kts) {
            const int k_lo = k_base + (kt + 1) * 64;
            #pragma unroll
            for (int j = 0; j < 4; ++j) {
                int c = t + j * 256, row = c >> 4, ch = c & 15;
                stg[j] = *(const bf16x8*)&Kp[base + (size_t)(k_lo + row) * LAT + ch * 8];
            }
            #pragma unroll
            for (int j = 0; j < 4; ++j) {
                int c = t + j * 256, row = c >> 3, ch = c & 7;
                stg[4 + j] = *(const bf16x8*)&VpT[vbase + (size_t)row * NTOK + k_lo + ch * 8];
            }
        }
        __syncthreads();

        f32x16 SA[2];
        #pragma unroll
        for (int kb = 0; kb < 2; ++kb) {
            f32x16 s = {};
            const int kr = kb * 32 + lane31;
            #pragma unroll
            for (int ds = 0; ds < 8; ++ds) {
                bf16x8 kf = *(const bf16x8*)(ldsK +
                    ((kr * 256 + ds * 32 + hi * 16) ^ ((kr & 7) << 4)));
                s = __builtin_amdgcn_mfma_f32_32x32x16_bf16(kf, qf[ds], s, 0, 0, 0);
            }
            SA[kb] = s;
        }

        float pmax = -1e30f;
        #pragma unroll
        for (int kb = 0; kb < 2; ++kb)
            #pragma unroll
            for (int r = 0; r < 16; ++r) pmax = fmaxf(pmax, SA[kb][r]);
        pmax = fmaxf(pmax, __shfl_xor(pmax, 32));

        if (__any(pmax > mrun + 8.f)) {      // defer-max (T13)
            float mnew = fmaxf(mrun, pmax);
            float al = exp2f(mrun - mnew);
            mrun = mnew;
            lrun *= al;
            #pragma unroll
            for (int db = 0; db < 4; ++db)
                #pragma unroll
                for (int r = 0; r < 16; ++r) OA[db][r] *= al;
        }

        float ls = 0.f;
        #pragma unroll
        for (int kb = 0; kb < 2; ++kb) {
            float p[16];
            #pragma unroll
            for (int r = 0; r < 16; ++r) {
                p[r] = exp2f(SA[kb][r] - mrun);
                ls += p[r];
            }
            unsigned a0 = cvtpk(p[0], p[1]),  a1 = cvtpk(p[2], p[3]);
            unsigned a2 = cvtpk(p[4], p[5]),  a3 = cvtpk(p[6], p[7]);
            permswap(a0, a2); permswap(a1, a3);
            unsigned b0 = cvtpk(p[8], p[9]),   b1 = cvtpk(p[10], p[11]);
            unsigned b2 = cvtpk(p[12], p[13]), b3 = cvtpk(p[14], p[15]);
            permswap(b0, b2); permswap(b1, b3);
            union { unsigned u[4]; bf16x8 v; } f0 = {{a0, a1, a2, a3}};
            union { unsigned u[4]; bf16x8 v; } f1 = {{b0, b1, b2, b3}};

            #pragma unroll
            for (int db = 0; db < 4; ++db) {
                const int d = db * 32 + lane31;
                bf16x8 vfA = *(const bf16x8*)(ldsV +
                    ((d * 128 + (kb * 2 + 0) * 32 + hi * 16) ^ ((d & 7) << 4)));
                OA[db] = __builtin_amdgcn_mfma_f32_32x32x16_bf16(vfA, f0.v, OA[db], 0, 0, 0);
                bf16x8 vfB = *(const bf16x8*)(ldsV +
                    ((d * 128 + (kb * 2 + 1) * 32 + hi * 16) ^ ((d & 7) << 4)));
                OA[db] = __builtin_amdgcn_mfma_f32_32x32x16_bf16(vfB, f1.v, OA[db], 0, 0, 0);
            }
        }
        ls += __shfl_xor(ls, 32);
        lrun += ls;
        __syncthreads();
    }

    if constexpr (NSPLIT == 1) {
        const float inv = 1.0f / lrun;
        float* dst = &Y[base + (size_t)(wq + lane31) * LAT];
        #pragma unroll
        for (int db = 0; db < 4; ++db)
            #pragma unroll
            for (int g = 0; g < 4; ++g) {
                f32x4 v;
                #pragma unroll
                for (int j = 0; j < 4; ++j) v[j] = OA[db][4 * g + j] * inv;
                *(f32x4*)&dst[db * 32 + 8 * g + 4 * hi] = v;
            }
    } else {
        const size_t prow = (size_t)ck * MTOT + (size_t)b * NTOK + wq + lane31;
        unsigned short* dst = &Opart[prow * LAT];
        #pragma unroll
        for (int db = 0; db < 4; ++db)
            #pragma unroll
            for (int g = 0; g < 4; ++g) {
                union { unsigned short s[4]; unsigned long long q; } pk;
                #pragma unroll
                for (int j = 0; j < 4; ++j) pk.s[j] = f2bf(OA[db][4 * g + j]);
                *(unsigned long long*)&dst[db * 32 + 8 * g + 4 * hi] = pk.q;
            }
        if (l < 32) ml[prow] = make_float2(mrun, lrun);
    }
}

// ===========================================================================
// merge2: Y = (sum_c 2^{m_c-M} O_c) / (sum_c 2^{m_c-M} l_c). (unchanged)
// ===========================================================================
__global__ __launch_bounds__(256) void merge2(const unsigned short* __restrict__ Opart,
                                              const float2* __restrict__ ml,
                                              float* __restrict__ Y) {
    const int idx = blockIdx.x * 256 + threadIdx.x;
    const int row = idx >> 4, cc = (idx & 15) * 8;
    float m[SPLIT], li[SPLIT];
    float M = -1e30f;
    #pragma unroll
    for (int c = 0; c < SPLIT; ++c) {
        float2 p = ml[(size_t)c * MTOT + row];
        m[c] = p.x; li[c] = p.y; M = fmaxf(M, m[c]);
    }
    float L = 0.f, wg[SPLIT];
    #pragma unroll
    for (int c = 0; c < SPLIT; ++c) { wg[c] = exp2f(m[c] - M); L += wg[c] * li[c]; }
    float acc[8] = {};
    #pragma unroll
    for (int c = 0; c < SPLIT; ++c) {
        bf16x8 v = *(const bf16x8*)&Opart[((size_t)c * MTOT + row) * LAT + cc];
        #pragma unroll
        for (int j = 0; j < 8; ++j)
            acc[j] += wg[c] * bf2f((unsigned short)v[j]);
    }
    const float inv = 1.f / L;
    f32x4 o0, o1;
    #pragma unroll
    for (int j = 0; j < 4; ++j) { o0[j] = acc[j] * inv; o1[j] = acc[4 + j] * inv; }
    *(f32x4*)&Y[(size_t)row * LAT + cc] = o0;
    *(f32x4*)&Y[(size_t)row * LAT + cc + 4] = o1;
}

// ===========================================================================
extern "C" void kernel_launch(void* const* d_in, const int* in_sizes, int n_in,
                              void* d_out, int out_size, void* d_ws, size_t ws_size,
                              hipStream_t stream) {
    const float* Q  = (const float*)d_in[0];
    // d_in[1] (K) ignored by reference
    const float* V  = (const float*)d_in[2];
    const float* Wk = (const float*)d_in[3];
    const float* bk = (const float*)d_in[4];
    const float* Wq = (const float*)d_in[5];
    const float* bq = (const float*)d_in[6];
    const float* Wv = (const float*)d_in[7];
    const float* bv = (const float*)d_in[8];
    float* Y = (float*)d_out;

    char* ws = (char*)d_ws;
    unsigned short* Kp    = (unsigned short*)(ws);                 // 4 MB
    unsigned short* Qp    = (unsigned short*)(ws + (4 << 20));     // 4 MB
    unsigned short* VpT   = (unsigned short*)(ws + (8 << 20));     // 4 MB
    unsigned short* Wcomb = (unsigned short*)(ws + (12 << 20));    // 512 KB
    float*          bqk   = (float*)         (ws + 13107200);      // 512 B
    float2*         ml    = (float2*)        (ws + 13107712);      // 512 KB
    unsigned short* Opart = (unsigned short*)(ws + 13632000);      // 16 MB
    const size_t need_split = 13632000 + (size_t)SPLIT * MTOT * LAT * 2;

    fuse_w<<<dim3(4, 128), 256, 0, stream>>>(Wq, Wk, bk, bq, Wcomb, bqk);
    proj_qk<<<dim3(512), 256, 0, stream>>>(Q, Wcomb, bk, bqk, Kp, Qp);
    proj_v<<<dim3(512), 256, 0, stream>>>(V, Wv, bv, VpT);

    if (ws_size >= need_split) {
        attn2<SPLIT><<<dim3(32 * NB * SPLIT), 256, 0, stream>>>(Qp, Kp, VpT, Opart, ml, nullptr);
        merge2<<<dim3(MTOT * 16 / 256), 256, 0, stream>>>(Opart, ml, Y);
    } else {
        attn2<1><<<dim3(32 * NB), 256, 0, stream>>>(Qp, Kp, VpT, nullptr, nullptr, Y);
    }
}